// Round 5
// baseline (124.630 us; speedup 1.0000x reference)
//
#include <hip/hip_runtime.h>

#define B_ROWS   8192
#define BMASK    8191
#define DIM      128
#define CTILE    64          // columns per tile
#define CHUNK    8           // col-tiles per block
#define BLK64    16384       // bytes per packed 64-row block (64*128*2)

typedef __attribute__((ext_vector_type(8)))  __bf16 bf16x8;
typedef __attribute__((ext_vector_type(16))) float  f32x16;

// sqrt(log2(e)/0.07) folded symmetrically into both row normalizations.
#define RBSCALE 4.5398159f

__device__ __forceinline__ float fast_exp2(float x) {
    return exp2f(x);
}

// 64 rows per block: norm -> scale -> bf16 -> k-major packed layout
// packed[row>>6][granule=k/8][row&63][8 bf16]. Coalesced 256B store segments.
// Block 0 also zeroes the accumulators.
__global__ __launch_bounds__(256)
void prep_kernel(const float* __restrict__ e1, const float* __restrict__ e2,
                 char* __restrict__ p1, char* __restrict__ p2,
                 float* __restrict__ acc) {
    if (blockIdx.x == 0 && threadIdx.x < 4) acc[threadIdx.x] = 0.f;
    const int rb = blockIdx.x;            // 64-row block id, 0..255
    const float* src; char* dst; int rb_loc;
    if (rb < 128) { src = e1; dst = p1; rb_loc = rb; }
    else          { src = e2; dst = p2; rb_loc = rb - 128; }

    const int t  = threadIdx.x;
    const int rr = t >> 2;                // row within block, 0..63
    const int q  = t & 3;                 // quarter of the k-dim, 32 floats each

    const float* rp = src + (size_t)(rb_loc * 64 + rr) * DIM + q * 32;
    float4 f[8];
    float ss = 0.f;
#pragma unroll
    for (int j = 0; j < 8; ++j) {
        f[j] = ((const float4*)rp)[j];
        ss += f[j].x * f[j].x + f[j].y * f[j].y + f[j].z * f[j].z + f[j].w * f[j].w;
    }
    // quad reduce: lanes 4r..4r+3 hold quarters of row r
    ss += __shfl_xor(ss, 1);
    ss += __shfl_xor(ss, 2);
    const float rbn = RBSCALE / sqrtf(ss);

    char* db = dst + (size_t)rb_loc * BLK64;
#pragma unroll
    for (int j = 0; j < 4; ++j) {
        bf16x8 v;
        float4 a = f[2 * j], b = f[2 * j + 1];
        v[0] = (__bf16)(a.x * rbn); v[1] = (__bf16)(a.y * rbn);
        v[2] = (__bf16)(a.z * rbn); v[3] = (__bf16)(a.w * rbn);
        v[4] = (__bf16)(b.x * rbn); v[5] = (__bf16)(b.y * rbn);
        v[6] = (__bf16)(b.z * rbn); v[7] = (__bf16)(b.w * rbn);
        *(bf16x8*)(db + (size_t)(q * 4 + j) * 1024 + (size_t)rr * 16) = v;
    }
}

template <bool MASKED>
__device__ __forceinline__ float tile_sum(const f32x16& a0, const f32x16& a1,
                                          int i00, int c) {
    float s = 0.f;
#pragma unroll
    for (int g = 0; g < 2; ++g) {
        const f32x16& a = g ? a1 : a0;
        int ib = i00 + g * 32;
#pragma unroll
        for (int r = 0; r < 16; ++r) {
            float ev = fast_exp2(a[r]);
            if (MASKED) {
                int i = ib + (r & 3) + 8 * (r >> 2);   // m74/m101 C/D row map
                int d = (c - i) & BMASK;               // (c-i) mod B
                s += (d > i) ? ev : 0.f;
            } else {
                s += ev;
            }
        }
    }
    return s;
}

// Persistent-panel blocks: 128-row A panel in registers, loop over 64-col B tiles
// double-buffered via async global_load_lds. 256 threads = 4 waves:
// w>>1 = row half (64 rows), w&1 = col half (32 cols).
__global__ __launch_bounds__(256, 4)
void pair_kernel(const char* __restrict__ P1, const char* __restrict__ P2,
                 float* __restrict__ accg, float* __restrict__ out,
                 int nz0, int nblocks) {
    __shared__ __align__(16) __bf16 Bbuf[2][8192];   // 2 x 16 KB
    __shared__ float red[4];

    const int tid = threadIdx.x;
    const int b   = blockIdx.x;

    // ---- block -> (z, panel p, tile chunk [k0,k1)) ----
    int z, p, k0, k1;
    if (b < nz0) {
        z = 0;
        int accb = 0; p = 0;
        for (;; ++p) {
            int i0t = 128 * p;
            int e1t = (i0t > 128) ? i0t : 128;
            int cnt = 2 + (B_ROWS - e1t) / 64;
            int nb  = (cnt + CHUNK - 1) / CHUNK;
            if (b < accb + nb) {
                int s = b - accb;
                k0 = s * CHUNK;
                k1 = (k0 + CHUNK < cnt) ? (k0 + CHUNK) : cnt;
                break;
            }
            accb += nb;
        }
    } else {
        z = 1;
        int j = b - nz0;
        p  = j >> 4;                 // 128 tiles / 8 per chunk = 16 chunks per panel
        k0 = (j & 15) * CHUNK;
        k1 = k0 + CHUNK;
    }
    const int i0 = 128 * p;
    const int e1 = (i0 > 128) ? i0 : 128;

    const char* Bpack = (z == 0) ? P1 : P2;

    auto tile_c0 = [&](int k) -> int {
        if (z) return k * CTILE;
        int e = (k == 0) ? 64 : e1 + (k - 1) * 64;
        return (i0 + e) & BMASK;
    };
    auto tile_masked = [&](int k) -> bool {
        if (z) return false;
        int e = (k == 0) ? 64 : e1 + (k - 1) * 64;
        return (e < i0 + 256) || (e > 8128);
    };

    const int w  = tid >> 6, lane = tid & 63;
    const int w2 = w >> 1, wc = w & 1;
    const int l  = lane & 31, h = lane >> 5;

    // ---- A panel -> registers: rows i0 + w2*64 + [0,64), k-major packed ----
    bf16x8 af[2][8];
    {
        const char* ap = P1 + (size_t)(p * 2 + w2) * BLK64;
#pragma unroll
        for (int g = 0; g < 2; ++g)
#pragma unroll
            for (int s = 0; s < 8; ++s)
                af[g][s] = *(const bf16x8*)(ap + (size_t)(s * 2 + h) * 1024
                                               + (size_t)(g * 32 + l) * 16);
    }

    // ---- async stage: 16 KB tile, lane-linear (256 thr x 16 B x 4 rounds) ----
    auto stage = [&](int bufi, int k) {
        const char* gp = Bpack + (size_t)(tile_c0(k) >> 6) * BLK64 + (size_t)tid * 16;
        char*       lp = (char*)&Bbuf[bufi][0] + (size_t)tid * 16;
#pragma unroll
        for (int r = 0; r < 4; ++r)
            __builtin_amdgcn_global_load_lds(
                (const __attribute__((address_space(1))) unsigned int*)(gp + r * 4096),
                (__attribute__((address_space(3))) unsigned int*)(lp + r * 4096),
                16, 0, 0);
    };

    const int i00 = i0 + w2 * 64 + 4 * h;   // epilogue row base for this lane
    const int cb  = wc * 32 + l;            // col offset within tile

    float sacc = 0.f;
    stage(0, k0);
    int cur = 0;
    for (int k = k0; k < k1; ++k) {
        __syncthreads();                     // buf[cur] staged; prev compute done
        if (k + 1 < k1) stage(cur ^ 1, k + 1);

        f32x16 a0, a1;
#pragma unroll
        for (int r = 0; r < 16; ++r) { a0[r] = 0.f; a1[r] = 0.f; }

        const char* bb = (const char*)&Bbuf[cur][0] + (size_t)cb * 16 + (size_t)h * 1024;
#pragma unroll
        for (int s = 0; s < 8; ++s) {
            bf16x8 bf = *(const bf16x8*)(bb + (size_t)s * 2048);
            a0 = __builtin_amdgcn_mfma_f32_32x32x16_bf16(af[0][s], bf, a0, 0, 0, 0);
            a1 = __builtin_amdgcn_mfma_f32_32x32x16_bf16(af[1][s], bf, a1, 0, 0, 0);
        }

        int c = tile_c0(k) + cb;
        sacc += tile_masked(k) ? tile_sum<true >(a0, a1, i00, c)
                               : tile_sum<false>(a0, a1, i00, c);
        cur ^= 1;
    }

#pragma unroll
    for (int o = 32; o > 0; o >>= 1) sacc += __shfl_down(sacc, o);
    if (lane == 0) red[w] = sacc;
    __syncthreads();
    if (tid == 0) {
        atomicAdd(&accg[z], red[0] + red[1] + red[2] + red[3]);
        __threadfence();
        unsigned prev = atomicAdd((unsigned*)&accg[2], 1u);
        if (prev == (unsigned)(nblocks - 1)) {
            float l1 = atomicAdd(&accg[0], 0.f);
            float l2 = atomicAdd(&accg[1], 0.f);
            out[0] = -logf(l1 / l2);
        }
    }
}

extern "C" void kernel_launch(void* const* d_in, const int* in_sizes, int n_in,
                              void* d_out, int out_size, void* d_ws, size_t ws_size,
                              hipStream_t stream) {
    (void)in_sizes; (void)n_in; (void)out_size; (void)ws_size;
    const float* e1 = (const float*)d_in[0];
    const float* e2 = (const float*)d_in[1];
    float* out = (float*)d_out;
    char*  ws  = (char*)d_ws;

    float* acc = (float*)ws;                       // 16 B: l1, l2, counter, pad
    char*  p1  = ws + 4096;                        // 2 MB packed E1
    char*  p2  = ws + 4096 + 2097152;              // 2 MB packed E2

    // z0 block count (must match device-side mapping)
    int nz0 = 0;
    for (int p = 0; p < 64; ++p) {
        int i0 = 128 * p;
        int e1t = (i0 > 128) ? i0 : 128;
        int cnt = 2 + (B_ROWS - e1t) / 64;
        nz0 += (cnt + CHUNK - 1) / CHUNK;
    }
    int nblocks = nz0 + 1024;

    prep_kernel<<<dim3(256), dim3(256), 0, stream>>>(e1, e2, p1, p2, acc);
    pair_kernel<<<dim3(nblocks), dim3(256), 0, stream>>>(p1, p2, acc, out, nz0, nblocks);
}